// Round 11
// baseline (232.583 us; speedup 1.0000x reference)
//
#include <hip/hip_runtime.h>
#include <hip/hip_bf16.h>
#include <cstdint>

#define B_ 8
#define C_ 256
#define N_ 4096

typedef __bf16 bf16;
typedef __bf16 bf16x8 __attribute__((ext_vector_type(8)));
typedef float f32x4 __attribute__((ext_vector_type(4)));
typedef float f32x16 __attribute__((ext_vector_type(16)));
typedef unsigned int u32;

__device__ __forceinline__ void async_ld16(const void* g, void* l) {
  __builtin_amdgcn_global_load_lds(
      (const __attribute__((address_space(1))) void*)g,
      (__attribute__((address_space(3))) void*)l, 16, 0, 0);
}

__device__ __forceinline__ float bh2f(unsigned short u) {
  union { u32 i; float f; } x; x.i = ((u32)u) << 16; return x.f;
}
__device__ __forceinline__ unsigned short f2bh(float f) {
  union { float f; u32 i; } x; x.f = f;
  u32 i = x.i + 0x7fffu + ((x.i >> 16) & 1u);
  return (unsigned short)(i >> 16);
}

// Per-wave dtype sniff (fp32 vs bf16 buffer), validated R2/R3.
__device__ __forceinline__ bool wave_sniff_fp32(const unsigned short* p) {
  int l = threadIdx.x & 63;
  unsigned short u = p[2 * l];
  int e = (u >> 7) & 0xff;
  unsigned long long m = __ballot(e >= 112 && e <= 142);
  return __popcll(m) < 32;
}

// ---------------- kernel 0 (merged): blocks 0..255 = Mt; 256.. = transpose ----------
__global__ __launch_bounds__(256) void k_pre(const void* __restrict__ Wqv,
                                             const void* __restrict__ Wkv,
                                             const void* __restrict__ Fv,
                                             unsigned short* __restrict__ Mt,
                                             unsigned short* __restrict__ Ft) {
  __shared__ float wkcol[C_];
  __shared__ unsigned short tile[64 * 66];
  int bid = blockIdx.x;
  int t = threadIdx.x;
  if (bid < 256) {
    bool fq = wave_sniff_fp32((const unsigned short*)Wqv);
    bool fk = wave_sniff_fp32((const unsigned short*)Wkv);
    int d = bid, c = t;
    if (fk)
      wkcol[c] = ((const float*)Wkv)[c * C_ + d];
    else
      wkcol[c] = bh2f(((const unsigned short*)Wkv)[c * C_ + d]);
    __syncthreads();
    float acc = 0.f;
    if (fq) {
      for (int e0 = 0; e0 < C_; e0 += 16) {
        float wq[16];
#pragma unroll
        for (int j = 0; j < 16; ++j) wq[j] = ((const float*)Wqv)[(e0 + j) * C_ + c];
#pragma unroll
        for (int j = 0; j < 16; ++j) acc += wkcol[e0 + j] * wq[j];
      }
    } else {
      for (int e0 = 0; e0 < C_; e0 += 16) {
        float wq[16];
#pragma unroll
        for (int j = 0; j < 16; ++j) wq[j] = bh2f(((const unsigned short*)Wqv)[(e0 + j) * C_ + c]);
#pragma unroll
        for (int j = 0; j < 16; ++j) acc += wkcol[e0 + j] * wq[j];
      }
    }
    Mt[(size_t)d * C_ + c] = f2bh(acc);
    return;
  }
  bool f32 = wave_sniff_fp32((const unsigned short*)Fv);
  int id = bid - 256;
  int n0 = (id & 63) * 64, c0 = ((id >> 6) & 3) * 64, b = id >> 8;
#pragma unroll
  for (int p = 0; p < 2; ++p) {
    int c = (t >> 3) + 32 * p;
    int n = (t & 7) * 8;
    size_t off = (size_t)(b * C_ + c0 + c) * N_ + n0 + n;
    unsigned short vals[8];
    if (f32) {
      const float* src = (const float*)Fv + off;
      float4 v0 = *(const float4*)(src);
      float4 v1 = *(const float4*)(src + 4);
      vals[0] = f2bh(v0.x); vals[1] = f2bh(v0.y); vals[2] = f2bh(v0.z); vals[3] = f2bh(v0.w);
      vals[4] = f2bh(v1.x); vals[5] = f2bh(v1.y); vals[6] = f2bh(v1.z); vals[7] = f2bh(v1.w);
    } else {
      uint4 v = *(const uint4*)((const unsigned short*)Fv + off);
      vals[0] = (unsigned short)(v.x & 0xffffu); vals[1] = (unsigned short)(v.x >> 16);
      vals[2] = (unsigned short)(v.y & 0xffffu); vals[3] = (unsigned short)(v.y >> 16);
      vals[4] = (unsigned short)(v.z & 0xffffu); vals[5] = (unsigned short)(v.z >> 16);
      vals[6] = (unsigned short)(v.w & 0xffffu); vals[7] = (unsigned short)(v.w >> 16);
    }
#pragma unroll
    for (int s = 0; s < 8; ++s) tile[c * 66 + n + s] = vals[s];
  }
  __syncthreads();
#pragma unroll
  for (int p = 0; p < 4; ++p) {
    int n = (t >> 4) + 16 * p;
    int cq = (t & 15) * 4;
    unsigned short e0 = tile[(cq + 0) * 66 + n];
    unsigned short e1 = tile[(cq + 1) * 66 + n];
    unsigned short e2 = tile[(cq + 2) * 66 + n];
    unsigned short e3 = tile[(cq + 3) * 66 + n];
    uint2 o;
    o.x = ((u32)e1 << 16) | e0;
    o.y = ((u32)e3 << 16) | e2;
    *(uint2*)(Ft + ((size_t)(b * N_ + n0 + n) * C_ + c0 + cq)) = o;
  }
}

// ---------------- kernel 2: G[b,n,d] = sum_c Ft[b,n,c] * Mt[d,c] ----------------
// 64n x 128d tiles, 32KB LDS, grid 1024, 4 blocks/CU (R9-measured config).
__global__ __launch_bounds__(256, 4) void k_proj(const bf16* __restrict__ Ft,
                                                 const bf16* __restrict__ Mt,
                                                 bf16* __restrict__ G) {
  __shared__ bf16 As[8 * 64 * 32];  // chunk kc at kc*2048; [row][32c] swizzled
  int n0 = blockIdx.x * 64;
  int b = blockIdx.y;
  int d0 = blockIdx.z * 128;
  int t = threadIdx.x, w = t >> 6, l = t & 63;
  int lr = l & 15, lq = l >> 4;
  int wn = w * 32;
  const size_t fbase = (size_t)b * N_ * C_;

  int srow = t >> 2;
  int schunk = ((t & 3) ^ ((t >> 3) & 3)) * 8;
#pragma unroll
  for (int kc = 0; kc < 8; ++kc)
    async_ld16(Ft + fbase + (size_t)(n0 + srow) * C_ + kc * 32 + schunk,
               As + kc * 2048 + t * 8);

  bf16x8 bb[2][8];
#pragma unroll
  for (int j = 0; j < 2; ++j)
#pragma unroll
    for (int kc = 0; kc < 8; ++kc)
      bb[j][kc] = *(const bf16x8*)(Mt + (size_t)(d0 + wn + 16 * j + lr) * C_ + kc * 32 + lq * 8);

  __syncthreads();  // vmcnt drained + barrier
  int rchunk = (lq ^ ((lr >> 1) & 3)) * 8;
  f32x4 acc[4][2] = {};
#pragma unroll
  for (int kc = 0; kc < 8; ++kc) {
#pragma unroll
    for (int i = 0; i < 4; ++i) {
      bf16x8 a = *(const bf16x8*)(As + kc * 2048 + (16 * i + lr) * 32 + rchunk);
#pragma unroll
      for (int j = 0; j < 2; ++j)
        acc[i][j] = __builtin_amdgcn_mfma_f32_16x16x32_bf16(a, bb[j][kc], acc[i][j], 0, 0, 0);
    }
  }
#pragma unroll
  for (int i = 0; i < 4; ++i)
#pragma unroll
    for (int j = 0; j < 2; ++j)
#pragma unroll
      for (int r = 0; r < 4; ++r) {
        int row = n0 + 16 * i + lq * 4 + r;
        int col = d0 + wn + 16 * j + lr;
        G[fbase + (size_t)row * C_ + col] = (bf16)acc[i][j][r];
      }
}

// ---------------- kernel 3: attention row sums + diagonal (32x32x16 MFMA) --------
// grid 1024: b=bid&7, q=K-quarter, ntile (128 Q-rows). 4 blocks/CU, 32KB staged.
// R11: the two 32-row K-subtiles are processed SEQUENTIALLY with ONE acc tile
// (R10's acc[2] pushed live regs >128 at (256,4) -> scratch spill, FETCH 4.5x).
// Live state now ~96 regs: a[16]=64 VGPR + acc=16 + part=16 (R8-proven load).
__global__ __launch_bounds__(256, 4) void k_attn(const bf16* __restrict__ G,
                                                 const bf16* __restrict__ Ft,
                                                 float* __restrict__ snn,
                                                 float* __restrict__ lsum) {
  __shared__ bf16 Ks[64 * 256];  // 32 KB; row m at m*256; granule g at g^(m&31)
  int bid = blockIdx.x;
  int b = bid & 7, q = (bid >> 3) & 3, ntile = bid >> 5;
  int n0 = ntile * 128;
  int t = threadIdx.x, w = t >> 6, l = t & 63;
  int lm = l & 31, hi = l >> 5;
  int wrow = w * 32;
  const size_t gbase = (size_t)b * N_ * C_;

  // A-frags: A[m=lm][k=kc*16+hi*8+j] from G row n0+wrow+lm (R8/R10-proven layout)
  bf16x8 a[16];
#pragma unroll
  for (int kc = 0; kc < 16; ++kc)
    a[kc] = *(const bf16x8*)(G + gbase + (size_t)(n0 + wrow + lm) * C_ + kc * 16 + hi * 8);

  float part[16];
#pragma unroll
  for (int s = 0; s < 16; ++s) part[s] = 0.f;

  int m_base = q * 1024;

  for (int it = 0; it < 16; ++it) {
    int m0 = m_base + it * 64;
    __syncthreads();  // prior iteration's LDS reads complete
    // staging: instr i covers LDS elems (i*256+t)*8; row=(i*256+t)>>5, col=t&31,
    // source granule = col ^ (row&31)  (XOR self-inverse matches read side)
#pragma unroll
    for (int i = 0; i < 8; ++i) {
      int row = i * 8 + (t >> 5);
      int gsrc = (t & 31) ^ (row & 31);
      async_ld16(Ft + gbase + (size_t)(m0 + row) * C_ + gsrc * 8,
                 Ks + i * 2048 + t * 8);
    }
    __syncthreads();  // vmcnt drained + barrier: staged data visible
    for (int mt = 0; mt < 2; ++mt) {
      f32x16 acc = {};
#pragma unroll
      for (int kc = 0; kc < 16; ++kc) {
        int gp = (kc * 2 + hi) ^ lm;  // stored col for granule (kc*2+hi) of row lm
        bf16x8 bb = *(const bf16x8*)(Ks + (mt * 32 + lm) * 256 + gp * 8);
        acc = __builtin_amdgcn_mfma_f32_32x32x16_bf16(a[kc], bb, acc, 0, 0, 0);
      }
      bool dit = (m0 + mt * 32 == n0 + wrow);
#pragma unroll
      for (int reg = 0; reg < 16; ++reg) {
        float e = __expf(acc[reg]);
        part[reg] += e;
        if (dit) {
          int rloc = (reg & 3) + 8 * (reg >> 2) + 4 * hi;
          if (lm == rloc) snn[b * N_ + n0 + wrow + rloc] = e;
        }
      }
    }
  }

  // butterfly over the 32 lm-lanes (hi bit untouched; rows private to (reg,hi))
#pragma unroll
  for (int s = 0; s < 16; ++s) {
    float v = part[s];
    v += __shfl_xor(v, 1);
    v += __shfl_xor(v, 2);
    v += __shfl_xor(v, 4);
    v += __shfl_xor(v, 8);
    v += __shfl_xor(v, 16);
    part[s] = v;
  }
  if (lm == 0) {
#pragma unroll
    for (int reg = 0; reg < 16; ++reg) {
      int rloc = (reg & 3) + 8 * (reg >> 2) + 4 * hi;
      lsum[((size_t)q * B_ + b) * N_ + n0 + wrow + rloc] = part[reg];
    }
  }
}

// ---------------- kernel 4: out = F * snn/(sum_q lsum * (1+1e-8)) ----------------
__global__ __launch_bounds__(256) void k_scale(const void* __restrict__ Fv,
                                               const float* __restrict__ snn,
                                               const float* __restrict__ lsum,
                                               void* __restrict__ Outv) {
  bool f32 = wave_sniff_fp32((const unsigned short*)Fv);
  int g = blockIdx.x * 256 + threadIdx.x;
  size_t base = (size_t)g * 8;
  int n = (int)(base & (N_ - 1));
  int b = (int)(base >> 20);
  float4 s0 = *(const float4*)(snn + (size_t)b * N_ + n);
  float4 s1 = *(const float4*)(snn + (size_t)b * N_ + n + 4);
  float ls[8];
#pragma unroll
  for (int k = 0; k < 8; ++k) ls[k] = 0.f;
#pragma unroll
  for (int p = 0; p < 4; ++p) {
    float4 l0 = *(const float4*)(lsum + ((size_t)p * B_ + b) * N_ + n);
    float4 l1 = *(const float4*)(lsum + ((size_t)p * B_ + b) * N_ + n + 4);
    ls[0] += l0.x; ls[1] += l0.y; ls[2] += l0.z; ls[3] += l0.w;
    ls[4] += l1.x; ls[5] += l1.y; ls[6] += l1.z; ls[7] += l1.w;
  }
  const float c1 = 1.0f + 1e-8f;
  float dd[8];
  dd[0] = s0.x / (ls[0] * c1); dd[1] = s0.y / (ls[1] * c1);
  dd[2] = s0.z / (ls[2] * c1); dd[3] = s0.w / (ls[3] * c1);
  dd[4] = s1.x / (ls[4] * c1); dd[5] = s1.y / (ls[5] * c1);
  dd[6] = s1.z / (ls[6] * c1); dd[7] = s1.w / (ls[7] * c1);
  if (f32) {
    const float* F = (const float*)Fv + base;
    float* O = (float*)Outv + base;
    float4 a0 = *(const float4*)(F);
    float4 a1 = *(const float4*)(F + 4);
    float4 o0, o1;
    o0.x = a0.x * dd[0]; o0.y = a0.y * dd[1]; o0.z = a0.z * dd[2]; o0.w = a0.w * dd[3];
    o1.x = a1.x * dd[4]; o1.y = a1.y * dd[5]; o1.z = a1.z * dd[6]; o1.w = a1.w * dd[7];
    *(float4*)(O) = o0;
    *(float4*)(O + 4) = o1;
  } else {
    uint4 v = *(const uint4*)((const unsigned short*)Fv + base);
    u32 vv[4] = {v.x, v.y, v.z, v.w};
    u32 o[4];
#pragma unroll
    for (int k = 0; k < 4; ++k) {
      float lo = bh2f((unsigned short)(vv[k] & 0xffffu)) * dd[2 * k];
      float hi = bh2f((unsigned short)(vv[k] >> 16)) * dd[2 * k + 1];
      o[k] = ((u32)f2bh(hi) << 16) | f2bh(lo);
    }
    uint4 ov; ov.x = o[0]; ov.y = o[1]; ov.z = o[2]; ov.w = o[3];
    *(uint4*)((unsigned short*)Outv + base) = ov;
  }
}

extern "C" void kernel_launch(void* const* d_in, const int* in_sizes, int n_in,
                              void* d_out, int out_size, void* d_ws, size_t ws_size,
                              hipStream_t stream) {
  (void)in_sizes; (void)n_in; (void)out_size; (void)ws_size;
  const void* F = d_in[0];
  const void* Wq = d_in[1];
  const void* Wk = d_in[2];
  char* ws = (char*)d_ws;
  bf16* Ft = (bf16*)(ws);                         // 16 MiB
  bf16* G = (bf16*)(ws + (16u << 20));            // 16 MiB
  char* tail = ws + (32u << 20);
  float* snn = (float*)(tail);                    // 128 KiB
  float* lsum = (float*)(tail + 131072);          // 512 KiB (4 partials)
  bf16* Mt = (bf16*)(tail + 131072 + 524288);     // 128 KiB

  k_pre<<<256 + 2048, 256, 0, stream>>>(Wq, Wk, F, (unsigned short*)Mt, (unsigned short*)Ft);
  k_proj<<<dim3(N_ / 64, B_, 2), 256, 0, stream>>>(Ft, Mt, G);
  k_attn<<<1024, 256, 0, stream>>>(G, Ft, snn, lsum);
  k_scale<<<(B_ * C_ * N_ / 8) / 256, 256, 0, stream>>>(F, snn, lsum, d_out);
}

// Round 12
// 194.699 us; speedup vs baseline: 1.1946x; 1.1946x over previous
//
#include <hip/hip_runtime.h>
#include <hip/hip_bf16.h>
#include <cstdint>

#define B_ 8
#define C_ 256
#define N_ 4096

typedef __bf16 bf16;
typedef __bf16 bf16x8 __attribute__((ext_vector_type(8)));
typedef float f32x4 __attribute__((ext_vector_type(4)));
typedef unsigned int u32;

__device__ __forceinline__ void async_ld16(const void* g, void* l) {
  __builtin_amdgcn_global_load_lds(
      (const __attribute__((address_space(1))) void*)g,
      (__attribute__((address_space(3))) void*)l, 16, 0, 0);
}

__device__ __forceinline__ float bh2f(unsigned short u) {
  union { u32 i; float f; } x; x.i = ((u32)u) << 16; return x.f;
}
__device__ __forceinline__ unsigned short f2bh(float f) {
  union { float f; u32 i; } x; x.f = f;
  u32 i = x.i + 0x7fffu + ((x.i >> 16) & 1u);
  return (unsigned short)(i >> 16);
}

// Per-wave dtype sniff (fp32 vs bf16 buffer), validated R2/R3.
__device__ __forceinline__ bool wave_sniff_fp32(const unsigned short* p) {
  int l = threadIdx.x & 63;
  unsigned short u = p[2 * l];
  int e = (u >> 7) & 0xff;
  unsigned long long m = __ballot(e >= 112 && e <= 142);
  return __popcll(m) < 32;
}

// ---------------- kernel 0 (merged): blocks 0..255 = Mt; 256.. = transpose ----------
__global__ __launch_bounds__(256) void k_pre(const void* __restrict__ Wqv,
                                             const void* __restrict__ Wkv,
                                             const void* __restrict__ Fv,
                                             unsigned short* __restrict__ Mt,
                                             unsigned short* __restrict__ Ft) {
  __shared__ float wkcol[C_];
  __shared__ unsigned short tile[64 * 66];
  int bid = blockIdx.x;
  int t = threadIdx.x;
  if (bid < 256) {
    bool fq = wave_sniff_fp32((const unsigned short*)Wqv);
    bool fk = wave_sniff_fp32((const unsigned short*)Wkv);
    int d = bid, c = t;
    if (fk)
      wkcol[c] = ((const float*)Wkv)[c * C_ + d];
    else
      wkcol[c] = bh2f(((const unsigned short*)Wkv)[c * C_ + d]);
    __syncthreads();
    float acc = 0.f;
    if (fq) {
      for (int e0 = 0; e0 < C_; e0 += 16) {
        float wq[16];
#pragma unroll
        for (int j = 0; j < 16; ++j) wq[j] = ((const float*)Wqv)[(e0 + j) * C_ + c];
#pragma unroll
        for (int j = 0; j < 16; ++j) acc += wkcol[e0 + j] * wq[j];
      }
    } else {
      for (int e0 = 0; e0 < C_; e0 += 16) {
        float wq[16];
#pragma unroll
        for (int j = 0; j < 16; ++j) wq[j] = bh2f(((const unsigned short*)Wqv)[(e0 + j) * C_ + c]);
#pragma unroll
        for (int j = 0; j < 16; ++j) acc += wkcol[e0 + j] * wq[j];
      }
    }
    Mt[(size_t)d * C_ + c] = f2bh(acc);
    return;
  }
  bool f32 = wave_sniff_fp32((const unsigned short*)Fv);
  int id = bid - 256;
  int n0 = (id & 63) * 64, c0 = ((id >> 6) & 3) * 64, b = id >> 8;
#pragma unroll
  for (int p = 0; p < 2; ++p) {
    int c = (t >> 3) + 32 * p;
    int n = (t & 7) * 8;
    size_t off = (size_t)(b * C_ + c0 + c) * N_ + n0 + n;
    unsigned short vals[8];
    if (f32) {
      const float* src = (const float*)Fv + off;
      float4 v0 = *(const float4*)(src);
      float4 v1 = *(const float4*)(src + 4);
      vals[0] = f2bh(v0.x); vals[1] = f2bh(v0.y); vals[2] = f2bh(v0.z); vals[3] = f2bh(v0.w);
      vals[4] = f2bh(v1.x); vals[5] = f2bh(v1.y); vals[6] = f2bh(v1.z); vals[7] = f2bh(v1.w);
    } else {
      uint4 v = *(const uint4*)((const unsigned short*)Fv + off);
      vals[0] = (unsigned short)(v.x & 0xffffu); vals[1] = (unsigned short)(v.x >> 16);
      vals[2] = (unsigned short)(v.y & 0xffffu); vals[3] = (unsigned short)(v.y >> 16);
      vals[4] = (unsigned short)(v.z & 0xffffu); vals[5] = (unsigned short)(v.z >> 16);
      vals[6] = (unsigned short)(v.w & 0xffffu); vals[7] = (unsigned short)(v.w >> 16);
    }
#pragma unroll
    for (int s = 0; s < 8; ++s) tile[c * 66 + n + s] = vals[s];
  }
  __syncthreads();
  // R12: widened output — thread owns (n, 8-c octet), 2 uint4 stores
#pragma unroll
  for (int p = 0; p < 2; ++p) {
    int n = (t >> 3) + 32 * p;
    int c8 = (t & 7) * 8;
    u32 o[4];
#pragma unroll
    for (int k = 0; k < 4; ++k) {
      unsigned short lo = tile[(c8 + 2 * k) * 66 + n];
      unsigned short hi = tile[(c8 + 2 * k + 1) * 66 + n];
      o[k] = ((u32)hi << 16) | lo;
    }
    uint4 ov; ov.x = o[0]; ov.y = o[1]; ov.z = o[2]; ov.w = o[3];
    *(uint4*)(Ft + ((size_t)(b * N_ + n0 + n) * C_ + c0 + c8)) = ov;
  }
}

// ---------------- kernel 2: G[b,n,d] = sum_c Ft[b,n,c] * Mt[d,c] ----------------
// 64n x 128d tiles, 32KB LDS, grid 1024, 4 blocks/CU (R9-measured config).
__global__ __launch_bounds__(256, 4) void k_proj(const bf16* __restrict__ Ft,
                                                 const bf16* __restrict__ Mt,
                                                 bf16* __restrict__ G) {
  __shared__ bf16 As[8 * 64 * 32];  // chunk kc at kc*2048; [row][32c] swizzled
  int n0 = blockIdx.x * 64;
  int b = blockIdx.y;
  int d0 = blockIdx.z * 128;
  int t = threadIdx.x, w = t >> 6, l = t & 63;
  int lr = l & 15, lq = l >> 4;
  int wn = w * 32;
  const size_t fbase = (size_t)b * N_ * C_;

  int srow = t >> 2;
  int schunk = ((t & 3) ^ ((t >> 3) & 3)) * 8;
#pragma unroll
  for (int kc = 0; kc < 8; ++kc)
    async_ld16(Ft + fbase + (size_t)(n0 + srow) * C_ + kc * 32 + schunk,
               As + kc * 2048 + t * 8);

  bf16x8 bb[2][8];
#pragma unroll
  for (int j = 0; j < 2; ++j)
#pragma unroll
    for (int kc = 0; kc < 8; ++kc)
      bb[j][kc] = *(const bf16x8*)(Mt + (size_t)(d0 + wn + 16 * j + lr) * C_ + kc * 32 + lq * 8);

  __syncthreads();  // vmcnt drained + barrier
  int rchunk = (lq ^ ((lr >> 1) & 3)) * 8;
  f32x4 acc[4][2] = {};
#pragma unroll
  for (int kc = 0; kc < 8; ++kc) {
#pragma unroll
    for (int i = 0; i < 4; ++i) {
      bf16x8 a = *(const bf16x8*)(As + kc * 2048 + (16 * i + lr) * 32 + rchunk);
#pragma unroll
      for (int j = 0; j < 2; ++j)
        acc[i][j] = __builtin_amdgcn_mfma_f32_16x16x32_bf16(a, bb[j][kc], acc[i][j], 0, 0, 0);
    }
  }
#pragma unroll
  for (int i = 0; i < 4; ++i)
#pragma unroll
    for (int j = 0; j < 2; ++j)
#pragma unroll
      for (int r = 0; r < 4; ++r) {
        int row = n0 + 16 * i + lq * 4 + r;
        int col = d0 + wn + 16 * j + lr;
        G[fbase + (size_t)row * C_ + col] = (bf16)acc[i][j][r];
      }
}

// ---------------- kernel 3: attention row sums + diagonal (R9-proven 16x16) ------
// Launched TWICE with grid 512 (qbase 0 / 2) so each dispatch ~38-40 us — drops
// the top-5 visibility threshold and surfaces aux kernels for the next round.
__global__ __launch_bounds__(256, 4) void k_attn(const bf16* __restrict__ G,
                                                 const bf16* __restrict__ Ft,
                                                 float* __restrict__ snn,
                                                 float* __restrict__ lsum,
                                                 int qbase) {
  __shared__ bf16 Ks[8 * 64 * 32];  // 32 KB; chunk kc at kc*2048; chunk-swizzled
  int bid = blockIdx.x;
  int b = bid & 7, q = qbase + ((bid >> 3) & 1), ntile = bid >> 4;
  int n0 = ntile * 128;
  int t = threadIdx.x, w = t >> 6, l = t & 63;
  int lr = l & 15, lq = l >> 4;
  int wrow = w * 32;
  const size_t gbase = (size_t)b * N_ * C_;

  bf16x8 a[2][8];
#pragma unroll
  for (int i = 0; i < 2; ++i)
#pragma unroll
    for (int kc = 0; kc < 8; ++kc)
      a[i][kc] = *(const bf16x8*)(G + gbase + (size_t)(n0 + wrow + 16 * i + lr) * C_ + kc * 32 + lq * 8);

  float part[8];
#pragma unroll
  for (int s = 0; s < 8; ++s) part[s] = 0.f;

  int m_base = q * 1024;
  bool has_diag = (q == (ntile >> 3));
  int d0 = (ntile & 7) * 2;

  int srow = t >> 2;
  int schunk = ((t & 3) ^ ((t >> 3) & 3)) * 8;
  int rchunk = (lq ^ ((lr >> 1) & 3)) * 8;

  for (int it = 0; it < 16; ++it) {
    int m0 = m_base + it * 64;
    __syncthreads();  // prior iteration's LDS reads complete
#pragma unroll
    for (int kc = 0; kc < 8; ++kc)
      async_ld16(Ft + gbase + (size_t)(m0 + srow) * C_ + kc * 32 + schunk,
                 Ks + kc * 2048 + t * 8);
    __syncthreads();  // vmcnt drained + barrier: staged data visible
    f32x4 acc[2][4] = {};
#pragma unroll
    for (int kc = 0; kc < 8; ++kc) {
      bf16x8 bb[4];
#pragma unroll
      for (int j = 0; j < 4; ++j)
        bb[j] = *(const bf16x8*)(Ks + kc * 2048 + (16 * j + lr) * 32 + rchunk);
#pragma unroll
      for (int i = 0; i < 2; ++i)
#pragma unroll
        for (int j = 0; j < 4; ++j)
          acc[i][j] = __builtin_amdgcn_mfma_f32_16x16x32_bf16(a[i][kc], bb[j], acc[i][j], 0, 0, 0);
    }
    bool dit = has_diag && ((it >> 1) == (ntile & 7));
#pragma unroll
    for (int i = 0; i < 2; ++i)
#pragma unroll
      for (int j = 0; j < 4; ++j)
#pragma unroll
        for (int r = 0; r < 4; ++r) {
          float e = __expf(acc[i][j][r]);
          part[i * 4 + r] += e;
          if (dit) {
            int rloc = wrow + 16 * i + lq * 4 + r;
            int cloc = 16 * j + lr;
            if ((it - d0) * 64 + cloc == rloc) snn[b * N_ + n0 + rloc] = e;
          }
        }
  }

#pragma unroll
  for (int s = 0; s < 8; ++s) {
    float v = part[s];
    v += __shfl_xor(v, 1);
    v += __shfl_xor(v, 2);
    v += __shfl_xor(v, 4);
    v += __shfl_xor(v, 8);
    part[s] = v;
  }
  if (lr == 0) {
#pragma unroll
    for (int i = 0; i < 2; ++i)
#pragma unroll
      for (int r = 0; r < 4; ++r)
        lsum[((size_t)q * B_ + b) * N_ + n0 + wrow + 16 * i + lq * 4 + r] = part[i * 4 + r];
  }
}

// ---------------- kernel 4: out = F * snn/(sum_q lsum * (1+1e-8)) ----------------
__global__ __launch_bounds__(256) void k_scale(const void* __restrict__ Fv,
                                               const float* __restrict__ snn,
                                               const float* __restrict__ lsum,
                                               void* __restrict__ Outv) {
  bool f32 = wave_sniff_fp32((const unsigned short*)Fv);
  int g = blockIdx.x * 256 + threadIdx.x;
  size_t base = (size_t)g * 8;
  int n = (int)(base & (N_ - 1));
  int b = (int)(base >> 20);
  float4 s0 = *(const float4*)(snn + (size_t)b * N_ + n);
  float4 s1 = *(const float4*)(snn + (size_t)b * N_ + n + 4);
  float ls[8];
#pragma unroll
  for (int k = 0; k < 8; ++k) ls[k] = 0.f;
#pragma unroll
  for (int p = 0; p < 4; ++p) {
    float4 l0 = *(const float4*)(lsum + ((size_t)p * B_ + b) * N_ + n);
    float4 l1 = *(const float4*)(lsum + ((size_t)p * B_ + b) * N_ + n + 4);
    ls[0] += l0.x; ls[1] += l0.y; ls[2] += l0.z; ls[3] += l0.w;
    ls[4] += l1.x; ls[5] += l1.y; ls[6] += l1.z; ls[7] += l1.w;
  }
  const float c1 = 1.0f + 1e-8f;
  float dd[8];
  dd[0] = s0.x / (ls[0] * c1); dd[1] = s0.y / (ls[1] * c1);
  dd[2] = s0.z / (ls[2] * c1); dd[3] = s0.w / (ls[3] * c1);
  dd[4] = s1.x / (ls[4] * c1); dd[5] = s1.y / (ls[5] * c1);
  dd[6] = s1.z / (ls[6] * c1); dd[7] = s1.w / (ls[7] * c1);
  if (f32) {
    const float* F = (const float*)Fv + base;
    float* O = (float*)Outv + base;
    float4 a0 = *(const float4*)(F);
    float4 a1 = *(const float4*)(F + 4);
    float4 o0, o1;
    o0.x = a0.x * dd[0]; o0.y = a0.y * dd[1]; o0.z = a0.z * dd[2]; o0.w = a0.w * dd[3];
    o1.x = a1.x * dd[4]; o1.y = a1.y * dd[5]; o1.z = a1.z * dd[6]; o1.w = a1.w * dd[7];
    *(float4*)(O) = o0;
    *(float4*)(O + 4) = o1;
  } else {
    uint4 v = *(const uint4*)((const unsigned short*)Fv + base);
    u32 vv[4] = {v.x, v.y, v.z, v.w};
    u32 o[4];
#pragma unroll
    for (int k = 0; k < 4; ++k) {
      float lo = bh2f((unsigned short)(vv[k] & 0xffffu)) * dd[2 * k];
      float hi = bh2f((unsigned short)(vv[k] >> 16)) * dd[2 * k + 1];
      o[k] = ((u32)f2bh(hi) << 16) | f2bh(lo);
    }
    uint4 ov; ov.x = o[0]; ov.y = o[1]; ov.z = o[2]; ov.w = o[3];
    *(uint4*)((unsigned short*)Outv + base) = ov;
  }
}

extern "C" void kernel_launch(void* const* d_in, const int* in_sizes, int n_in,
                              void* d_out, int out_size, void* d_ws, size_t ws_size,
                              hipStream_t stream) {
  (void)in_sizes; (void)n_in; (void)out_size; (void)ws_size;
  const void* F = d_in[0];
  const void* Wq = d_in[1];
  const void* Wk = d_in[2];
  char* ws = (char*)d_ws;
  bf16* Ft = (bf16*)(ws);                         // 16 MiB
  bf16* G = (bf16*)(ws + (16u << 20));            // 16 MiB
  char* tail = ws + (32u << 20);
  float* snn = (float*)(tail);                    // 128 KiB
  float* lsum = (float*)(tail + 131072);          // 512 KiB (4 partials)
  bf16* Mt = (bf16*)(tail + 131072 + 524288);     // 128 KiB

  k_pre<<<256 + 2048, 256, 0, stream>>>(Wq, Wk, F, (unsigned short*)Mt, (unsigned short*)Ft);
  k_proj<<<dim3(N_ / 64, B_, 2), 256, 0, stream>>>(Ft, Mt, G);
  k_attn<<<512, 256, 0, stream>>>(G, Ft, snn, lsum, 0);
  k_attn<<<512, 256, 0, stream>>>(G, Ft, snn, lsum, 2);
  k_scale<<<(B_ * C_ * N_ / 8) / 256, 256, 0, stream>>>(F, snn, lsum, d_out);
}

// Round 13
// 181.334 us; speedup vs baseline: 1.2826x; 1.0737x over previous
//
#include <hip/hip_runtime.h>
#include <hip/hip_bf16.h>
#include <cstdint>

#define B_ 8
#define C_ 256
#define N_ 4096

typedef __bf16 bf16;
typedef __bf16 bf16x8 __attribute__((ext_vector_type(8)));
typedef float f32x4 __attribute__((ext_vector_type(4)));
typedef unsigned int u32;

__device__ __forceinline__ void async_ld16(const void* g, void* l) {
  __builtin_amdgcn_global_load_lds(
      (const __attribute__((address_space(1))) void*)g,
      (__attribute__((address_space(3))) void*)l, 16, 0, 0);
}

__device__ __forceinline__ float bh2f(unsigned short u) {
  union { u32 i; float f; } x; x.i = ((u32)u) << 16; return x.f;
}
__device__ __forceinline__ unsigned short f2bh(float f) {
  union { float f; u32 i; } x; x.f = f;
  u32 i = x.i + 0x7fffu + ((x.i >> 16) & 1u);
  return (unsigned short)(i >> 16);
}

// Per-wave dtype sniff (fp32 vs bf16 buffer), validated R2/R3.
__device__ __forceinline__ bool wave_sniff_fp32(const unsigned short* p) {
  int l = threadIdx.x & 63;
  unsigned short u = p[2 * l];
  int e = (u >> 7) & 0xff;
  unsigned long long m = __ballot(e >= 112 && e <= 142);
  return __popcll(m) < 32;
}

// ---------------- kernel 0 (merged): blocks 0..255 = Mt; 256.. = transpose ----------
__global__ __launch_bounds__(256) void k_pre(const void* __restrict__ Wqv,
                                             const void* __restrict__ Wkv,
                                             const void* __restrict__ Fv,
                                             unsigned short* __restrict__ Mt,
                                             unsigned short* __restrict__ Ft) {
  __shared__ float wkcol[C_];
  __shared__ unsigned short tile[64 * 66];
  int bid = blockIdx.x;
  int t = threadIdx.x;
  if (bid < 256) {
    bool fq = wave_sniff_fp32((const unsigned short*)Wqv);
    bool fk = wave_sniff_fp32((const unsigned short*)Wkv);
    int d = bid, c = t;
    if (fk)
      wkcol[c] = ((const float*)Wkv)[c * C_ + d];
    else
      wkcol[c] = bh2f(((const unsigned short*)Wkv)[c * C_ + d]);
    __syncthreads();
    float acc = 0.f;
    if (fq) {
      for (int e0 = 0; e0 < C_; e0 += 16) {
        float wq[16];
#pragma unroll
        for (int j = 0; j < 16; ++j) wq[j] = ((const float*)Wqv)[(e0 + j) * C_ + c];
#pragma unroll
        for (int j = 0; j < 16; ++j) acc += wkcol[e0 + j] * wq[j];
      }
    } else {
      for (int e0 = 0; e0 < C_; e0 += 16) {
        float wq[16];
#pragma unroll
        for (int j = 0; j < 16; ++j) wq[j] = bh2f(((const unsigned short*)Wqv)[(e0 + j) * C_ + c]);
#pragma unroll
        for (int j = 0; j < 16; ++j) acc += wkcol[e0 + j] * wq[j];
      }
    }
    Mt[(size_t)d * C_ + c] = f2bh(acc);
    return;
  }
  bool f32 = wave_sniff_fp32((const unsigned short*)Fv);
  int id = bid - 256;
  int n0 = (id & 63) * 64, c0 = ((id >> 6) & 3) * 64, b = id >> 8;
#pragma unroll
  for (int p = 0; p < 2; ++p) {
    int c = (t >> 3) + 32 * p;
    int n = (t & 7) * 8;
    size_t off = (size_t)(b * C_ + c0 + c) * N_ + n0 + n;
    unsigned short vals[8];
    if (f32) {
      const float* src = (const float*)Fv + off;
      float4 v0 = *(const float4*)(src);
      float4 v1 = *(const float4*)(src + 4);
      vals[0] = f2bh(v0.x); vals[1] = f2bh(v0.y); vals[2] = f2bh(v0.z); vals[3] = f2bh(v0.w);
      vals[4] = f2bh(v1.x); vals[5] = f2bh(v1.y); vals[6] = f2bh(v1.z); vals[7] = f2bh(v1.w);
    } else {
      uint4 v = *(const uint4*)((const unsigned short*)Fv + off);
      vals[0] = (unsigned short)(v.x & 0xffffu); vals[1] = (unsigned short)(v.x >> 16);
      vals[2] = (unsigned short)(v.y & 0xffffu); vals[3] = (unsigned short)(v.y >> 16);
      vals[4] = (unsigned short)(v.z & 0xffffu); vals[5] = (unsigned short)(v.z >> 16);
      vals[6] = (unsigned short)(v.w & 0xffffu); vals[7] = (unsigned short)(v.w >> 16);
    }
#pragma unroll
    for (int s = 0; s < 8; ++s) tile[c * 66 + n + s] = vals[s];
  }
  __syncthreads();
  // widened output — thread owns (n, 8-c octet), 2 uint4 stores (R12-validated)
#pragma unroll
  for (int p = 0; p < 2; ++p) {
    int n = (t >> 3) + 32 * p;
    int c8 = (t & 7) * 8;
    u32 o[4];
#pragma unroll
    for (int k = 0; k < 4; ++k) {
      unsigned short lo = tile[(c8 + 2 * k) * 66 + n];
      unsigned short hi = tile[(c8 + 2 * k + 1) * 66 + n];
      o[k] = ((u32)hi << 16) | lo;
    }
    uint4 ov; ov.x = o[0]; ov.y = o[1]; ov.z = o[2]; ov.w = o[3];
    *(uint4*)(Ft + ((size_t)(b * N_ + n0 + n) * C_ + c0 + c8)) = ov;
  }
}

// ---------------- kernel 2: G[b,n,d] = sum_c Ft[b,n,c] * Mt[d,c] ----------------
// 64n x 128d tiles, 32KB LDS, grid 1024, 4 blocks/CU (R9-measured config).
// R13: epilogue round-trips C through LDS (reusing As) -> 4 coalesced uint4
// stores/thread instead of 32 scalar 2B stores.
__global__ __launch_bounds__(256, 4) void k_proj(const bf16* __restrict__ Ft,
                                                 const bf16* __restrict__ Mt,
                                                 bf16* __restrict__ G) {
  __shared__ bf16 As[8 * 64 * 32];  // chunk kc at kc*2048; [row][32c] swizzled
  int n0 = blockIdx.x * 64;
  int b = blockIdx.y;
  int d0 = blockIdx.z * 128;
  int t = threadIdx.x, w = t >> 6, l = t & 63;
  int lr = l & 15, lq = l >> 4;
  int wn = w * 32;
  const size_t fbase = (size_t)b * N_ * C_;

  int srow = t >> 2;
  int schunk = ((t & 3) ^ ((t >> 3) & 3)) * 8;
#pragma unroll
  for (int kc = 0; kc < 8; ++kc)
    async_ld16(Ft + fbase + (size_t)(n0 + srow) * C_ + kc * 32 + schunk,
               As + kc * 2048 + t * 8);

  bf16x8 bb[2][8];
#pragma unroll
  for (int j = 0; j < 2; ++j)
#pragma unroll
    for (int kc = 0; kc < 8; ++kc)
      bb[j][kc] = *(const bf16x8*)(Mt + (size_t)(d0 + wn + 16 * j + lr) * C_ + kc * 32 + lq * 8);

  __syncthreads();  // vmcnt drained + barrier
  int rchunk = (lq ^ ((lr >> 1) & 3)) * 8;
  f32x4 acc[4][2] = {};
#pragma unroll
  for (int kc = 0; kc < 8; ++kc) {
#pragma unroll
    for (int i = 0; i < 4; ++i) {
      bf16x8 a = *(const bf16x8*)(As + kc * 2048 + (16 * i + lr) * 32 + rchunk);
#pragma unroll
      for (int j = 0; j < 2; ++j)
        acc[i][j] = __builtin_amdgcn_mfma_f32_16x16x32_bf16(a, bb[j][kc], acc[i][j], 0, 0, 0);
    }
  }
  __syncthreads();  // all As reads complete; reuse As as C-staging
  // Cs: [64 rows][136 stride] u16 (272B rows: 16B-aligned, rows 4 dwords apart
  // -> scatter writes max 2-way bank aliasing = free per m136)
  unsigned short* Cs = (unsigned short*)As;
#pragma unroll
  for (int i = 0; i < 4; ++i)
#pragma unroll
    for (int j = 0; j < 2; ++j)
#pragma unroll
      for (int r = 0; r < 4; ++r)
        Cs[(16 * i + lq * 4 + r) * 136 + wn + 16 * j + lr] = f2bh(acc[i][j][r]);
  __syncthreads();
#pragma unroll
  for (int p = 0; p < 4; ++p) {
    int idx = p * 256 + t;
    int row = idx >> 4, c8 = idx & 15;
    uint4 v = *(const uint4*)(Cs + row * 136 + c8 * 8);
    *(uint4*)(G + fbase + (size_t)(n0 + row) * C_ + d0 + c8 * 8) = v;
  }
}

// ---------------- kernel 3: attention row sums + diagonal (R9-proven 16x16) ------
// grid 1024: b=bid&7 (XCD-local batch), q=K-quarter, ntile. 4 blocks/CU.
__global__ __launch_bounds__(256, 4) void k_attn(const bf16* __restrict__ G,
                                                 const bf16* __restrict__ Ft,
                                                 float* __restrict__ snn,
                                                 float* __restrict__ lsum) {
  __shared__ bf16 Ks[8 * 64 * 32];  // 32 KB; chunk kc at kc*2048; chunk-swizzled
  int bid = blockIdx.x;
  int b = bid & 7, q = (bid >> 3) & 3, ntile = bid >> 5;
  int n0 = ntile * 128;
  int t = threadIdx.x, w = t >> 6, l = t & 63;
  int lr = l & 15, lq = l >> 4;
  int wrow = w * 32;
  const size_t gbase = (size_t)b * N_ * C_;

  bf16x8 a[2][8];
#pragma unroll
  for (int i = 0; i < 2; ++i)
#pragma unroll
    for (int kc = 0; kc < 8; ++kc)
      a[i][kc] = *(const bf16x8*)(G + gbase + (size_t)(n0 + wrow + 16 * i + lr) * C_ + kc * 32 + lq * 8);

  float part[8];
#pragma unroll
  for (int s = 0; s < 8; ++s) part[s] = 0.f;

  int m_base = q * 1024;
  bool has_diag = (q == (ntile >> 3));
  int d0 = (ntile & 7) * 2;

  int srow = t >> 2;
  int schunk = ((t & 3) ^ ((t >> 3) & 3)) * 8;
  int rchunk = (lq ^ ((lr >> 1) & 3)) * 8;

  for (int it = 0; it < 16; ++it) {
    int m0 = m_base + it * 64;
    __syncthreads();  // prior iteration's LDS reads complete
#pragma unroll
    for (int kc = 0; kc < 8; ++kc)
      async_ld16(Ft + gbase + (size_t)(m0 + srow) * C_ + kc * 32 + schunk,
                 Ks + kc * 2048 + t * 8);
    __syncthreads();  // vmcnt drained + barrier: staged data visible
    f32x4 acc[2][4] = {};
#pragma unroll
    for (int kc = 0; kc < 8; ++kc) {
      bf16x8 bb[4];
#pragma unroll
      for (int j = 0; j < 4; ++j)
        bb[j] = *(const bf16x8*)(Ks + kc * 2048 + (16 * j + lr) * 32 + rchunk);
#pragma unroll
      for (int i = 0; i < 2; ++i)
#pragma unroll
        for (int j = 0; j < 4; ++j)
          acc[i][j] = __builtin_amdgcn_mfma_f32_16x16x32_bf16(a[i][kc], bb[j], acc[i][j], 0, 0, 0);
    }
    bool dit = has_diag && ((it >> 1) == (ntile & 7));
#pragma unroll
    for (int i = 0; i < 2; ++i)
#pragma unroll
      for (int j = 0; j < 4; ++j)
#pragma unroll
        for (int r = 0; r < 4; ++r) {
          float e = __expf(acc[i][j][r]);
          part[i * 4 + r] += e;
          if (dit) {
            int rloc = wrow + 16 * i + lq * 4 + r;
            int cloc = 16 * j + lr;
            if ((it - d0) * 64 + cloc == rloc) snn[b * N_ + n0 + rloc] = e;
          }
        }
  }

#pragma unroll
  for (int s = 0; s < 8; ++s) {
    float v = part[s];
    v += __shfl_xor(v, 1);
    v += __shfl_xor(v, 2);
    v += __shfl_xor(v, 4);
    v += __shfl_xor(v, 8);
    part[s] = v;
  }
  if (lr == 0) {
#pragma unroll
    for (int i = 0; i < 2; ++i)
#pragma unroll
      for (int r = 0; r < 4; ++r)
        lsum[((size_t)q * B_ + b) * N_ + n0 + wrow + 16 * i + lq * 4 + r] = part[i * 4 + r];
  }
}

// ---------------- kernel 4: out = F * snn/(sum_q lsum * (1+1e-8)) ----------------
__global__ __launch_bounds__(256) void k_scale(const void* __restrict__ Fv,
                                               const float* __restrict__ snn,
                                               const float* __restrict__ lsum,
                                               void* __restrict__ Outv) {
  bool f32 = wave_sniff_fp32((const unsigned short*)Fv);
  int g = blockIdx.x * 256 + threadIdx.x;
  size_t base = (size_t)g * 8;
  int n = (int)(base & (N_ - 1));
  int b = (int)(base >> 20);
  float4 s0 = *(const float4*)(snn + (size_t)b * N_ + n);
  float4 s1 = *(const float4*)(snn + (size_t)b * N_ + n + 4);
  float ls[8];
#pragma unroll
  for (int k = 0; k < 8; ++k) ls[k] = 0.f;
#pragma unroll
  for (int p = 0; p < 4; ++p) {
    float4 l0 = *(const float4*)(lsum + ((size_t)p * B_ + b) * N_ + n);
    float4 l1 = *(const float4*)(lsum + ((size_t)p * B_ + b) * N_ + n + 4);
    ls[0] += l0.x; ls[1] += l0.y; ls[2] += l0.z; ls[3] += l0.w;
    ls[4] += l1.x; ls[5] += l1.y; ls[6] += l1.z; ls[7] += l1.w;
  }
  const float c1 = 1.0f + 1e-8f;
  float dd[8];
  dd[0] = s0.x / (ls[0] * c1); dd[1] = s0.y / (ls[1] * c1);
  dd[2] = s0.z / (ls[2] * c1); dd[3] = s0.w / (ls[3] * c1);
  dd[4] = s1.x / (ls[4] * c1); dd[5] = s1.y / (ls[5] * c1);
  dd[6] = s1.z / (ls[6] * c1); dd[7] = s1.w / (ls[7] * c1);
  if (f32) {
    const float* F = (const float*)Fv + base;
    float* O = (float*)Outv + base;
    float4 a0 = *(const float4*)(F);
    float4 a1 = *(const float4*)(F + 4);
    float4 o0, o1;
    o0.x = a0.x * dd[0]; o0.y = a0.y * dd[1]; o0.z = a0.z * dd[2]; o0.w = a0.w * dd[3];
    o1.x = a1.x * dd[4]; o1.y = a1.y * dd[5]; o1.z = a1.z * dd[6]; o1.w = a1.w * dd[7];
    *(float4*)(O) = o0;
    *(float4*)(O + 4) = o1;
  } else {
    uint4 v = *(const uint4*)((const unsigned short*)Fv + base);
    u32 vv[4] = {v.x, v.y, v.z, v.w};
    u32 o[4];
#pragma unroll
    for (int k = 0; k < 4; ++k) {
      float lo = bh2f((unsigned short)(vv[k] & 0xffffu)) * dd[2 * k];
      float hi = bh2f((unsigned short)(vv[k] >> 16)) * dd[2 * k + 1];
      o[k] = ((u32)f2bh(hi) << 16) | f2bh(lo);
    }
    uint4 ov; ov.x = o[0]; ov.y = o[1]; ov.z = o[2]; ov.w = o[3];
    *(uint4*)((unsigned short*)Outv + base) = ov;
  }
}

extern "C" void kernel_launch(void* const* d_in, const int* in_sizes, int n_in,
                              void* d_out, int out_size, void* d_ws, size_t ws_size,
                              hipStream_t stream) {
  (void)in_sizes; (void)n_in; (void)out_size; (void)ws_size;
  const void* F = d_in[0];
  const void* Wq = d_in[1];
  const void* Wk = d_in[2];
  char* ws = (char*)d_ws;
  bf16* Ft = (bf16*)(ws);                         // 16 MiB
  bf16* G = (bf16*)(ws + (16u << 20));            // 16 MiB
  char* tail = ws + (32u << 20);
  float* snn = (float*)(tail);                    // 128 KiB
  float* lsum = (float*)(tail + 131072);          // 512 KiB (4 partials)
  bf16* Mt = (bf16*)(tail + 131072 + 524288);     // 128 KiB

  k_pre<<<256 + 2048, 256, 0, stream>>>(Wq, Wk, F, (unsigned short*)Mt, (unsigned short*)Ft);
  k_proj<<<dim3(N_ / 64, B_, 2), 256, 0, stream>>>(Ft, Mt, G);
  k_attn<<<1024, 256, 0, stream>>>(G, Ft, snn, lsum);
  k_scale<<<(B_ * C_ * N_ / 8) / 256, 256, 0, stream>>>(F, snn, lsum, d_out);
}